// Round 2
// baseline (523.568 us; speedup 1.0000x reference)
//
#include <hip/hip_runtime.h>

// B=128, K=1024 pairwise-distance adjacency + row softmax, single pass.
// R2: 4 rows per wave (amortize LDS column reads 4x), exp2-form math.
// Row max of exp(-d*p) is exactly 1.0 (d_ii == 0 computed directly), and
// softmax is shift-invariant -> no max pass; use exp(x) directly.

#define K_PTS 1024
#define RPW 4                       // rows per wave
#define ROWS_PER_BLOCK 16           // 4 waves * 4 rows
#define L2E 1.44269504088896340736f

__global__ __launch_bounds__(256, 4) void adj_softmax_kernel(
    const float* __restrict__ coords,   // [B, K, 3]
    const float* __restrict__ prec,     // [1]
    float* __restrict__ out) {          // [B, K, K]
  __shared__ float sx[K_PTS];
  __shared__ float sy[K_PTS];
  __shared__ float sz[K_PTS];

  const int tid  = threadIdx.x;
  const int lane = tid & 63;
  const int wave = tid >> 6;
  const int tilesPerBatch = K_PTS / ROWS_PER_BLOCK;      // 64
  const int b    = blockIdx.x / tilesPerBatch;
  const int tile = blockIdx.x % tilesPerBatch;

  const float p = prec[0];

  // ---- stage batch coords into LDS, deinterleaved (x|y|z) ----
  {
    const float* cb = coords + (size_t)b * (K_PTS * 3);
    const int p0 = tid * 4;                       // 4 points per thread
    const float4* src = (const float4*)(cb + (size_t)p0 * 3);
    float4 a0 = src[0];   // {x0,y0,z0,x1}
    float4 a1 = src[1];   // {y1,z1,x2,y2}
    float4 a2 = src[2];   // {z2,x3,y3,z3}
    sx[p0 + 0] = a0.x; sy[p0 + 0] = a0.y; sz[p0 + 0] = a0.z;
    sx[p0 + 1] = a0.w; sy[p0 + 1] = a1.x; sz[p0 + 1] = a1.y;
    sx[p0 + 2] = a1.z; sy[p0 + 2] = a1.w; sz[p0 + 2] = a2.x;
    sx[p0 + 3] = a2.y; sy[p0 + 3] = a2.z; sz[p0 + 3] = a2.w;
  }
  __syncthreads();

  const float qa = -p * L2E;        // exp(-p*d) == exp2(qa*d)

  const int i0 = tile * ROWS_PER_BLOCK + wave * RPW;   // first row of this wave
  float xi[RPW], yi[RPW], zi[RPW];
#pragma unroll
  for (int r = 0; r < RPW; ++r) {
    xi[r] = sx[i0 + r]; yi[r] = sy[i0 + r]; zi[r] = sz[i0 + r];
  }

  float4 ev[RPW][4];                // 64 VGPRs: held unnormalized row values
  float acc[RPW] = {0.f, 0.f, 0.f, 0.f};

#pragma unroll
  for (int t = 0; t < 4; ++t) {
    const int j0 = 4 * lane + 256 * t;            // 4 consecutive points
    float4 vx = *(const float4*)&sx[j0];          // ds_read_b128, amortized /4 rows
    float4 vy = *(const float4*)&sy[j0];
    float4 vz = *(const float4*)&sz[j0];

#pragma unroll
    for (int r = 0; r < RPW; ++r) {
      float dx, dy, dz, d, xv;
      float4 e4;

      dx = vx.x - xi[r]; dy = vy.x - yi[r]; dz = vz.x - zi[r];
      d  = fmaf(dx, dx, fmaf(dy, dy, dz * dz));
      xv = __builtin_amdgcn_exp2f(qa * d);
      e4.x = __builtin_amdgcn_exp2f(xv * L2E);

      dx = vx.y - xi[r]; dy = vy.y - yi[r]; dz = vz.y - zi[r];
      d  = fmaf(dx, dx, fmaf(dy, dy, dz * dz));
      xv = __builtin_amdgcn_exp2f(qa * d);
      e4.y = __builtin_amdgcn_exp2f(xv * L2E);

      dx = vx.z - xi[r]; dy = vy.z - yi[r]; dz = vz.z - zi[r];
      d  = fmaf(dx, dx, fmaf(dy, dy, dz * dz));
      xv = __builtin_amdgcn_exp2f(qa * d);
      e4.z = __builtin_amdgcn_exp2f(xv * L2E);

      dx = vx.w - xi[r]; dy = vy.w - yi[r]; dz = vz.w - zi[r];
      d  = fmaf(dx, dx, fmaf(dy, dy, dz * dz));
      xv = __builtin_amdgcn_exp2f(qa * d);
      e4.w = __builtin_amdgcn_exp2f(xv * L2E);

      ev[r][t] = e4;
      acc[r] += (e4.x + e4.y) + (e4.z + e4.w);
    }
  }

  // ---- wave-level reductions (64 lanes) for the softmax denominators ----
  float inv[RPW];
#pragma unroll
  for (int r = 0; r < RPW; ++r) {
    float a = acc[r];
#pragma unroll
    for (int off = 32; off > 0; off >>= 1) a += __shfl_xor(a, off, 64);
    inv[r] = 1.0f / a;
  }

  // ---- normalized, coalesced float4 stores: each row written exactly once ----
#pragma unroll
  for (int r = 0; r < RPW; ++r) {
    float* orow = out + ((size_t)b * K_PTS + (i0 + r)) * K_PTS;
    const float s = inv[r];
#pragma unroll
    for (int t = 0; t < 4; ++t) {
      float4 e4 = ev[r][t];
      e4.x *= s; e4.y *= s; e4.z *= s; e4.w *= s;
      *(float4*)&orow[4 * lane + 256 * t] = e4;
    }
  }
}

extern "C" void kernel_launch(void* const* d_in, const int* in_sizes, int n_in,
                              void* d_out, int out_size, void* d_ws, size_t ws_size,
                              hipStream_t stream) {
  const float* coords = (const float*)d_in[0];   // [B, K, 3] fp32
  const float* prec   = (const float*)d_in[1];   // [1] fp32
  float* out = (float*)d_out;                    // [B, K, K] fp32

  const int B = in_sizes[0] / (K_PTS * 3);       // 128
  const int grid = B * (K_PTS / ROWS_PER_BLOCK); // 128 * 64 = 8192 blocks

  adj_softmax_kernel<<<grid, 256, 0, stream>>>(coords, prec, out);
}